// Round 1
// baseline (223.529 us; speedup 1.0000x reference)
//
#include <hip/hip_runtime.h>
#include <hip/hip_bf16.h>

#define M_DIM 4096
#define N_DIM 4096
#define K_DIM 4096

typedef __attribute__((ext_vector_type(8))) __bf16 bf16x8;
typedef __attribute__((ext_vector_type(8))) short short8;
typedef __attribute__((ext_vector_type(8))) unsigned short ushort8;
typedef __attribute__((ext_vector_type(4))) float f32x4;

// ---------------------------------------------------------------------------
// async global->LDS, 16B per lane. LDS dest must be wave-uniform base + lane*16
// (we pass per-thread dest = base + tid*16 which satisfies this per-wave).
// size arg must be a literal constant (ICE).
// ---------------------------------------------------------------------------
__device__ __forceinline__ void gload_lds16(const void* g, void* l) {
    __builtin_amdgcn_global_load_lds(
        (const __attribute__((address_space(1))) void*)g,
        (__attribute__((address_space(3))) void*)l,
        16, 0, 0);
}

// ---------------------------------------------------------------------------
// fp32 -> bf16 conversion with optional runtime-threshold pruning.
// thrp == nullptr -> keep everything (weight path).
// 8 elems / thread / iter: 32B read, 16B write, fully coalesced.
// ---------------------------------------------------------------------------
__global__ void prune_cvt(const float* __restrict__ in,
                          unsigned short* __restrict__ out,
                          const float* __restrict__ thrp, int n8) {
    const float thr = thrp ? thrp[0] : -1.0f;  // abs(x) > -1 always true
    const int stride = gridDim.x * blockDim.x;
    for (int idx = blockIdx.x * blockDim.x + threadIdx.x; idx < n8; idx += stride) {
        const float4* p = reinterpret_cast<const float4*>(in) + 2 * (size_t)idx;
        float4 v0 = p[0];
        float4 v1 = p[1];
        float v[8] = {v0.x, v0.y, v0.z, v0.w, v1.x, v1.y, v1.z, v1.w};
        ushort8 o;
#pragma unroll
        for (int j = 0; j < 8; ++j) {
            float f = v[j];
            f = (fabsf(f) > thr) ? f : 0.0f;   // prune in fp32 (exact predicate)
            __hip_bfloat16 h = __float2bfloat16(f);
            o[j] = *reinterpret_cast<unsigned short*>(&h);
        }
        *reinterpret_cast<ushort8*>(out + 8 * (size_t)idx) = o;
    }
}

// ---------------------------------------------------------------------------
// C = A * B^T   (A: [M][K] bf16 row-major, B: [N][K] bf16 row-major, C: [M][N] f32)
// m97 structure: 128x128 tile, BK=32, 4 waves (2x2 of 64x64), 16x16x32 MFMA,
// global_load_lds(16B) staging, 2 barriers / K-step.
// ---------------------------------------------------------------------------
__global__ __launch_bounds__(256) void gemm_bt_bf16(
        const unsigned short* __restrict__ A,
        const unsigned short* __restrict__ B,
        float* __restrict__ C) {
    __shared__ __align__(16) unsigned short As[128 * 32];  // 8 KB
    __shared__ __align__(16) unsigned short Bs[128 * 32];  // 8 KB

    const int tid  = threadIdx.x;
    const int lane = tid & 63;
    const int wid  = tid >> 6;
    const int wr   = wid >> 1;        // wave row (0..1) -> 64-row strip
    const int wc   = wid & 1;         // wave col (0..1) -> 64-col strip
    const int bm   = blockIdx.y * 128;
    const int bn   = blockIdx.x * 128;

    // staging: thread t covers tile row t/4 (call0: rows 0..63, call1: 64..127),
    // K-bytes [(t%4)*16, +16). LDS dest = linear, base + tid*16 bytes.
    const int srow = tid >> 2;
    const int scol = (tid & 3) * 8;
    const unsigned short* Ag0 = A + (size_t)(bm + srow) * K_DIM + scol;
    const unsigned short* Ag1 = Ag0 + (size_t)64 * K_DIM;
    const unsigned short* Bg0 = B + (size_t)(bn + srow) * K_DIM + scol;
    const unsigned short* Bg1 = Bg0 + (size_t)64 * K_DIM;
    unsigned short* AsD0 = As + tid * 8;
    unsigned short* AsD1 = As + 2048 + tid * 8;
    unsigned short* BsD0 = Bs + tid * 8;
    unsigned short* BsD1 = Bs + 2048 + tid * 8;

    f32x4 acc[4][4] = {};

    // fragment addressing: lane holds row (lane&15), k = (lane>>4)*8 .. +8
    const int fr = lane & 15;
    const int kq = lane >> 4;
    const int aoff = (wr * 64 + fr) * 32 + kq * 8;  // + m*16*32
    const int boff = (wc * 64 + fr) * 32 + kq * 8;  // + n*16*32

    for (int k0 = 0; k0 < K_DIM; k0 += 32) {
        __syncthreads();   // previous iteration's LDS reads complete
        gload_lds16(Ag0 + k0, AsD0);
        gload_lds16(Ag1 + k0, AsD1);
        gload_lds16(Bg0 + k0, BsD0);
        gload_lds16(Bg1 + k0, BsD1);
        __syncthreads();   // compiler drains vmcnt(0) before s_barrier -> LDS valid

        bf16x8 a[4], b[4];
#pragma unroll
        for (int m = 0; m < 4; ++m) {
            short8 ra = *reinterpret_cast<const short8*>(As + aoff + m * 512);
            a[m] = __builtin_bit_cast(bf16x8, ra);
        }
#pragma unroll
        for (int n = 0; n < 4; ++n) {
            short8 rb = *reinterpret_cast<const short8*>(Bs + boff + n * 512);
            b[n] = __builtin_bit_cast(bf16x8, rb);
        }
#pragma unroll
        for (int m = 0; m < 4; ++m)
#pragma unroll
            for (int n = 0; n < 4; ++n)
                acc[m][n] = __builtin_amdgcn_mfma_f32_16x16x32_bf16(
                    a[m], b[n], acc[m][n], 0, 0, 0);
    }

    // C/D layout (m89-verified): col = lane&15, row = (lane>>4)*4 + reg
    const int crow0 = bm + wr * 64 + kq * 4;
    const int ccol0 = bn + wc * 64 + fr;
#pragma unroll
    for (int m = 0; m < 4; ++m)
#pragma unroll
        for (int n = 0; n < 4; ++n)
#pragma unroll
            for (int j = 0; j < 4; ++j)
                C[(size_t)(crow0 + m * 16 + j) * N_DIM + ccol0 + n * 16] =
                    acc[m][n][j];
}

// ---------------------------------------------------------------------------
// fp32 fallback (only if ws_size is too small for bf16 staging buffers).
// Classic 32x32 LDS-tiled vector GEMM, pruning fused into the A-tile load.
// ---------------------------------------------------------------------------
__global__ void gemm_f32_fallback(const float* __restrict__ A,
                                  const float* __restrict__ B,
                                  float* __restrict__ C,
                                  const float* __restrict__ thrp) {
    __shared__ float As[32][33];
    __shared__ float Bs[32][33];
    const float thr = thrp[0];
    const int tx = threadIdx.x, ty = threadIdx.y;
    const int row = blockIdx.y * 32 + ty;
    float acc = 0.0f;
    for (int k0 = 0; k0 < K_DIM; k0 += 32) {
        float a = A[(size_t)row * K_DIM + k0 + tx];
        As[ty][tx] = (fabsf(a) > thr) ? a : 0.0f;
        Bs[ty][tx] = B[(size_t)(blockIdx.x * 32 + ty) * K_DIM + k0 + tx];
        __syncthreads();
#pragma unroll 8
        for (int kk = 0; kk < 32; ++kk)
            acc += As[ty][kk] * Bs[tx][kk];
        __syncthreads();
    }
    C[(size_t)row * N_DIM + blockIdx.x * 32 + tx] = acc;
}

// ---------------------------------------------------------------------------
extern "C" void kernel_launch(void* const* d_in, const int* in_sizes, int n_in,
                              void* d_out, int out_size, void* d_ws, size_t ws_size,
                              hipStream_t stream) {
    const float* x    = (const float*)d_in[0];  // last_out [4096,4096] f32
    const float* w    = (const float*)d_in[1];  // weight   [4096,4096] f32
    const float* thrp = (const float*)d_in[2];  // threshold scalar f32
    float* out = (float*)d_out;

    const size_t elems = (size_t)M_DIM * K_DIM;
    if (ws_size >= 2 * elems * sizeof(unsigned short)) {
        unsigned short* Ab = (unsigned short*)d_ws;
        unsigned short* Bb = Ab + elems;
        const int n8 = (int)(elems / 8);
        prune_cvt<<<2048, 256, 0, stream>>>(x, Ab, thrp, n8);
        prune_cvt<<<2048, 256, 0, stream>>>(w, Bb, nullptr, n8);
        dim3 grid(N_DIM / 128, M_DIM / 128);
        gemm_bt_bf16<<<grid, 256, 0, stream>>>(Ab, Bb, out);
    } else {
        dim3 grid(N_DIM / 32, M_DIM / 32), blk(32, 32);
        gemm_f32_fallback<<<grid, blk, 0, stream>>>(x, w, out, thrp);
    }
}

// Round 2
// 150.684 us; speedup vs baseline: 1.4834x; 1.4834x over previous
//
#include <hip/hip_runtime.h>
#include <hip/hip_bf16.h>

#define M_DIM 4096
#define N_DIM 4096
#define K_DIM 4096

typedef __attribute__((ext_vector_type(8))) __bf16 bf16x8;
typedef __attribute__((ext_vector_type(8))) short short8;
typedef __attribute__((ext_vector_type(8))) unsigned short ushort8;
typedef __attribute__((ext_vector_type(4))) float f32x4;

// async global->LDS, 16B/lane. LDS dest is wave-uniform base + lane*16 (m104);
// we pass per-thread dest which per-wave is exactly base + lane*16.
__device__ __forceinline__ void gload_lds16(const void* g, void* l) {
    __builtin_amdgcn_global_load_lds(
        (const __attribute__((address_space(1))) void*)g,
        (__attribute__((address_space(3))) void*)l,
        16, 0, 0);
}

__device__ __forceinline__ bf16x8 ld8(const unsigned short* p) {
    short8 r = *reinterpret_cast<const short8*>(p);
    return __builtin_bit_cast(bf16x8, r);
}

// ---------------------------------------------------------------------------
// fp32 -> bf16 with optional runtime-threshold pruning (thrp==nullptr: keep all)
// ---------------------------------------------------------------------------
__global__ void prune_cvt(const float* __restrict__ in,
                          unsigned short* __restrict__ out,
                          const float* __restrict__ thrp, int n8) {
    const float thr = thrp ? thrp[0] : -1.0f;
    const int stride = gridDim.x * blockDim.x;
    for (int idx = blockIdx.x * blockDim.x + threadIdx.x; idx < n8; idx += stride) {
        const float4* p = reinterpret_cast<const float4*>(in) + 2 * (size_t)idx;
        float4 v0 = p[0];
        float4 v1 = p[1];
        float v[8] = {v0.x, v0.y, v0.z, v0.w, v1.x, v1.y, v1.z, v1.w};
        ushort8 o;
#pragma unroll
        for (int j = 0; j < 8; ++j) {
            float f = v[j];
            f = (fabsf(f) > thr) ? f : 0.0f;
            __hip_bfloat16 hh = __float2bfloat16(f);
            o[j] = *reinterpret_cast<unsigned short*>(&hh);
        }
        *reinterpret_cast<ushort8*>(out + 8 * (size_t)idx) = o;
    }
}

// ---------------------------------------------------------------------------
// C = A * B^T, 256x256 tile, BK=64, 8 waves, 8-phase counted-vmcnt pipeline.
// A: [M][K] bf16, B(=W): [N][K] bf16, C: [M][N] f32.
// LDS layout per buffer: A[256][64] then B[256][64], slot-swizzled:
//   element(row, logical col c) at row*64 + 8*((c>>3) ^ (row&7)) + (c&7)
// ---------------------------------------------------------------------------
__global__ __launch_bounds__(512, 2) void gemm_8phase(
        const unsigned short* __restrict__ A,
        const unsigned short* __restrict__ B,
        float* __restrict__ C) {
    __shared__ __align__(16) unsigned short lds[65536];  // 128 KB: A[2][16384], B[2][16384]

    const int tid  = threadIdx.x;
    const int lane = tid & 63;
    const int wid  = tid >> 6;
    const int wr   = wid >> 2;   // 0..1 : 128-row strip
    const int wc   = wid & 3;    // 0..3 : 64-col strip

    // XCD-aware bijective swizzle (256 blocks / 8 XCDs)
    const int bid = blockIdx.x;
    const int swz = (bid & 7) * 32 + (bid >> 3);
    const int bm = (swz >> 4) * 256;
    const int bn = (swz & 15) * 256;

    // ---- staging descriptors (per-wave-matched: each wave stages what it reads)
    // A-half `ah` staged by waves with wr==ah; load j covers rows [32j,32j+32)
    const int g  = tid & 255;
    const int ah = tid >> 8;
    const int arow = bm + ah * 128 + (g >> 3);
    const int acol = 8 * ((g & 7) ^ ((g >> 3) & 7));      // pre-swizzled source col
    const unsigned short* Asrc = A + (size_t)arow * K_DIM + acol;
    const int AdstE = ah * 8192 + g * 8;                  // linear LDS dest (elems)

    // B-quarter `wc` staged by waves {wc, wc+4}; load j covers rows [16j,16j+16)
    const int h = lane + 64 * wr;
    const int brow = bn + wc * 64 + (h >> 3);
    const int bcol = 8 * ((h & 7) ^ ((h >> 3) & 7));
    const unsigned short* Bsrc = B + (size_t)brow * K_DIM + bcol;
    const int BdstE = wc * 4096 + h * 8;

#define SA(dstb, j, kg) gload_lds16(Asrc + (size_t)(32*(j))*K_DIM + (kg), (dstb) + AdstE + 2048*(j))
#define SB(dstb, j, kg) gload_lds16(Bsrc + (size_t)(16*(j))*K_DIM + (kg), (dstb) + BdstE + 1024*(j))

    // ---- fragment read offsets (row&7 == fr&7 -> swizzle is thread-constant)
    const int fr  = lane & 15;
    const int kq4 = lane >> 4;
    const int rowOffA = (wr * 128 + fr) * 64;
    const int rowOffB = (wc * 64 + fr) * 64;
    const int sk0 = 8 * ((kq4    ) ^ (fr & 7));   // kk=0 slice
    const int sk1 = 8 * ((kq4 + 4) ^ (fr & 7));   // kk=1 slice

    f32x4 acc[8][4] = {};

#define MFMA16(q, A00, A10, A01, A11)                                                              \
    __builtin_amdgcn_s_setprio(1);                                                                 \
    _Pragma("unroll")                                                                              \
    for (int n = 0; n < 4; ++n) {                                                                  \
        acc[2*(q)][n]   = __builtin_amdgcn_mfma_f32_16x16x32_bf16(A00, bfr[n][0], acc[2*(q)][n], 0, 0, 0);   \
        acc[2*(q)+1][n] = __builtin_amdgcn_mfma_f32_16x16x32_bf16(A10, bfr[n][0], acc[2*(q)+1][n], 0, 0, 0); \
        acc[2*(q)][n]   = __builtin_amdgcn_mfma_f32_16x16x32_bf16(A01, bfr[n][1], acc[2*(q)][n], 0, 0, 0);   \
        acc[2*(q)+1][n] = __builtin_amdgcn_mfma_f32_16x16x32_bf16(A11, bfr[n][1], acc[2*(q)+1][n], 0, 0, 0); \
    }                                                                                              \
    __builtin_amdgcn_s_setprio(0);

    // ---- prologue: stage kt0 into buf0 (order B0..B3,A0..A3), enter invariant:
    // oldest 5 (all B + A0) resident, {A1,A2,A3} in flight  -> vmcnt(3)
    SB(lds + 32768, 0, 0); SB(lds + 32768, 1, 0); SB(lds + 32768, 2, 0); SB(lds + 32768, 3, 0);
    SA(lds,         0, 0); SA(lds,         1, 0); SA(lds,         2, 0); SA(lds,         3, 0);
    asm volatile("s_waitcnt vmcnt(3)" ::: "memory");
    asm volatile("s_barrier" ::: "memory");

    // ---- main loop: 64 K-tiles. Iter t computes buf[t&1], stages kt t+1 into buf[~t&1].
    // Ledger (per wave): end-ph0 vmcnt(6) [->A1 cur], ph1 vmcnt(7) [->A2],
    // ph2 vmcnt(8) [->A3], ph3 vmcnt(3) [->next B0-3+A0]. Never drains to 0.
    for (int t = 0; t < 64; ++t) {
        const int cur = t & 1, nxt = cur ^ 1;
        const unsigned short* Ab = lds + cur * 16384;
        const unsigned short* Bb = lds + 32768 + cur * 16384;
        unsigned short* AbN = lds + nxt * 16384;
        unsigned short* BbN = lds + 32768 + nxt * 16384;
        const int kn = (t < 63 ? (t + 1) : 63) * 64;   // clamped: last stage is dead data

        bf16x8 bfr[4][2];
        // ---------------- phase 0: m{0,1}; read all B-frags; stage B'0-3
        {
#pragma unroll
            for (int n = 0; n < 4; ++n) {
                bfr[n][0] = ld8(Bb + rowOffB + n * 1024 + sk0);
                bfr[n][1] = ld8(Bb + rowOffB + n * 1024 + sk1);
            }
            bf16x8 a00 = ld8(Ab + rowOffA + 0 * 1024 + sk0);
            bf16x8 a10 = ld8(Ab + rowOffA + 1 * 1024 + sk0);
            bf16x8 a01 = ld8(Ab + rowOffA + 0 * 1024 + sk1);
            bf16x8 a11 = ld8(Ab + rowOffA + 1 * 1024 + sk1);
            SB(BbN, 0, kn); SB(BbN, 1, kn); SB(BbN, 2, kn); SB(BbN, 3, kn);
            asm volatile("s_barrier" ::: "memory");
            MFMA16(0, a00, a10, a01, a11);
            asm volatile("s_waitcnt vmcnt(6)" ::: "memory");
            asm volatile("s_barrier" ::: "memory");
        }
        // ---------------- phase 1: m{2,3}; stage A'0,A'1
        {
            bf16x8 a00 = ld8(Ab + rowOffA + 2 * 1024 + sk0);
            bf16x8 a10 = ld8(Ab + rowOffA + 3 * 1024 + sk0);
            bf16x8 a01 = ld8(Ab + rowOffA + 2 * 1024 + sk1);
            bf16x8 a11 = ld8(Ab + rowOffA + 3 * 1024 + sk1);
            SA(AbN, 0, kn); SA(AbN, 1, kn);
            asm volatile("s_barrier" ::: "memory");
            MFMA16(1, a00, a10, a01, a11);
            asm volatile("s_waitcnt vmcnt(7)" ::: "memory");
            asm volatile("s_barrier" ::: "memory");
        }
        // ---------------- phase 2: m{4,5}; stage A'2,A'3
        {
            bf16x8 a00 = ld8(Ab + rowOffA + 4 * 1024 + sk0);
            bf16x8 a10 = ld8(Ab + rowOffA + 5 * 1024 + sk0);
            bf16x8 a01 = ld8(Ab + rowOffA + 4 * 1024 + sk1);
            bf16x8 a11 = ld8(Ab + rowOffA + 5 * 1024 + sk1);
            SA(AbN, 2, kn); SA(AbN, 3, kn);
            asm volatile("s_barrier" ::: "memory");
            MFMA16(2, a00, a10, a01, a11);
            asm volatile("s_waitcnt vmcnt(8)" ::: "memory");
            asm volatile("s_barrier" ::: "memory");
        }
        // ---------------- phase 3: m{6,7}; no staging
        {
            bf16x8 a00 = ld8(Ab + rowOffA + 6 * 1024 + sk0);
            bf16x8 a10 = ld8(Ab + rowOffA + 7 * 1024 + sk0);
            bf16x8 a01 = ld8(Ab + rowOffA + 6 * 1024 + sk1);
            bf16x8 a11 = ld8(Ab + rowOffA + 7 * 1024 + sk1);
            asm volatile("s_barrier" ::: "memory");
            MFMA16(3, a00, a10, a01, a11);
            asm volatile("s_waitcnt vmcnt(3)" ::: "memory");
            asm volatile("s_barrier" ::: "memory");
        }
    }

    asm volatile("s_waitcnt vmcnt(0)" ::: "memory");  // drain dead tail stages

    // C/D layout (m89): col = lane&15, row = (lane>>4)*4 + j
    const int crow = bm + wr * 128 + kq4 * 4;
    const int ccol = bn + wc * 64 + fr;
#pragma unroll
    for (int m = 0; m < 8; ++m)
#pragma unroll
        for (int n = 0; n < 4; ++n)
#pragma unroll
            for (int j = 0; j < 4; ++j)
                C[(size_t)(crow + m * 16 + j) * N_DIM + ccol + n * 16] = acc[m][n][j];
}

// ---------------------------------------------------------------------------
// fp32 fallback (only if ws too small)
// ---------------------------------------------------------------------------
__global__ void gemm_f32_fallback(const float* __restrict__ A,
                                  const float* __restrict__ B,
                                  float* __restrict__ C,
                                  const float* __restrict__ thrp) {
    __shared__ float As[32][33];
    __shared__ float Bs[32][33];
    const float thr = thrp[0];
    const int tx = threadIdx.x, ty = threadIdx.y;
    const int row = blockIdx.y * 32 + ty;
    float acc = 0.0f;
    for (int k0 = 0; k0 < K_DIM; k0 += 32) {
        float a = A[(size_t)row * K_DIM + k0 + tx];
        As[ty][tx] = (fabsf(a) > thr) ? a : 0.0f;
        Bs[ty][tx] = B[(size_t)(blockIdx.x * 32 + ty) * K_DIM + k0 + tx];
        __syncthreads();
#pragma unroll 8
        for (int kk = 0; kk < 32; ++kk)
            acc += As[ty][kk] * Bs[tx][kk];
        __syncthreads();
    }
    C[(size_t)row * N_DIM + blockIdx.x * 32 + tx] = acc;
}

// ---------------------------------------------------------------------------
extern "C" void kernel_launch(void* const* d_in, const int* in_sizes, int n_in,
                              void* d_out, int out_size, void* d_ws, size_t ws_size,
                              hipStream_t stream) {
    const float* x    = (const float*)d_in[0];
    const float* w    = (const float*)d_in[1];
    const float* thrp = (const float*)d_in[2];
    float* out = (float*)d_out;

    const size_t elems = (size_t)M_DIM * K_DIM;
    if (ws_size >= 2 * elems * sizeof(unsigned short)) {
        unsigned short* Ab = (unsigned short*)d_ws;
        unsigned short* Bb = Ab + elems;
        const int n8 = (int)(elems / 8);
        prune_cvt<<<2048, 256, 0, stream>>>(x, Ab, thrp, n8);
        prune_cvt<<<2048, 256, 0, stream>>>(w, Bb, nullptr, n8);
        gemm_8phase<<<dim3(256), dim3(512), 0, stream>>>(Ab, Bb, out);
    } else {
        dim3 grid(N_DIM / 32, M_DIM / 32), blk(32, 32);
        gemm_f32_fallback<<<grid, blk, 0, stream>>>(x, w, out, thrp);
    }
}

// Round 3
// 146.393 us; speedup vs baseline: 1.5269x; 1.0293x over previous
//
#include <hip/hip_runtime.h>
#include <hip/hip_bf16.h>

#define M_DIM 4096
#define N_DIM 4096
#define K_DIM 4096

typedef __attribute__((ext_vector_type(8))) __bf16 bf16x8;
typedef __attribute__((ext_vector_type(8))) short short8;
typedef __attribute__((ext_vector_type(8))) unsigned short ushort8;
typedef __attribute__((ext_vector_type(4))) float f32x4;

// async global->LDS, 16B/lane (m104: dest = wave-uniform base + lane*16)
__device__ __forceinline__ void gload_lds16(const void* g, void* l) {
    __builtin_amdgcn_global_load_lds(
        (const __attribute__((address_space(1))) void*)g,
        (__attribute__((address_space(3))) void*)l,
        16, 0, 0);
}

__device__ __forceinline__ bf16x8 ld8(const unsigned short* p) {
    short8 r = *reinterpret_cast<const short8*>(p);
    return __builtin_bit_cast(bf16x8, r);
}

// ---------------------------------------------------------------------------
// fused fp32->bf16 conversion: x (pruned) and w (unpruned) in ONE launch
// ---------------------------------------------------------------------------
__global__ void prune_cvt2(const float* __restrict__ x,
                           const float* __restrict__ w,
                           unsigned short* __restrict__ xb,
                           unsigned short* __restrict__ wb,
                           const float* __restrict__ thrp, int n8) {
    const float thr = thrp[0];
    const int stride = gridDim.x * blockDim.x;
    const int total = 2 * n8;
    for (int idx = blockIdx.x * blockDim.x + threadIdx.x; idx < total; idx += stride) {
        const bool isx = idx < n8;
        const int j = isx ? idx : idx - n8;
        const float* src = isx ? x : w;
        unsigned short* dst = isx ? xb : wb;
        const float te = isx ? thr : -1.0f;   // |v| > -1 always true -> keep all
        const float4* p = reinterpret_cast<const float4*>(src) + 2 * (size_t)j;
        float4 v0 = p[0];
        float4 v1 = p[1];
        float v[8] = {v0.x, v0.y, v0.z, v0.w, v1.x, v1.y, v1.z, v1.w};
        ushort8 o;
#pragma unroll
        for (int e = 0; e < 8; ++e) {
            float f = v[e];
            f = (fabsf(f) > te) ? f : 0.0f;   // prune in fp32 (exact predicate)
            __hip_bfloat16 hh = __float2bfloat16(f);
            o[e] = *reinterpret_cast<unsigned short*>(&hh);
        }
        *reinterpret_cast<ushort8*>(dst + 8 * (size_t)j) = o;
    }
}

// ---------------------------------------------------------------------------
// C = A * B^T, 256x256 tile, BK=64, 8 waves, 4-phase/K-tile pipeline with
// register-level A-fragment double-buffering (frags for phase p read during
// phase p-1) and ONE barrier per phase.
//
// LDS per buffer: A[256][64], B[256][64], slot-swizzled:
//   element(row, logical col c) at row*64 + 8*((c>>3) ^ (row&7)) + (c&7)
//
// vmcnt ledger (per thread; issues: ph0 +4 B', ph1 +2 A'01, ph2 +2 A'23):
//   ph0-end vmcnt(5): lands a2(t-1)  -> ph1 may read A(t)-j2
//   ph1-end vmcnt(6): lands a3(t-1)  -> ph2 may read A(t)-j3
//   ph2-end vmcnt(3): lands B'x4,a0' -> ph3 may pre-read A(t+1)-j0
//   ph3-end vmcnt(2): lands a1'      -> next ph0 may read A(t+1)-j1 + B(t+1)
// Every wait has >=1.5-phase slack; never drains to 0 in the loop.
// ---------------------------------------------------------------------------
__global__ __launch_bounds__(512, 2) void gemm_8phase(
        const unsigned short* __restrict__ A,
        const unsigned short* __restrict__ B,
        float* __restrict__ C) {
    __shared__ __align__(16) unsigned short lds[65536];  // 128 KB

    const int tid  = threadIdx.x;
    const int lane = tid & 63;
    const int wid  = tid >> 6;
    const int wr   = wid >> 2;   // 0..1 : 128-row strip
    const int wc   = wid & 3;    // 0..3 : 64-col strip

    // XCD-aware bijective swizzle (256 blocks / 8 XCDs)
    const int bid = blockIdx.x;
    const int swz = (bid & 7) * 32 + (bid >> 3);
    const int bm = (swz >> 4) * 256;
    const int bn = (swz & 15) * 256;

    // staging: A-half ah staged by threads [ah*256, ah*256+256); load j = rows [32j,+32)
    const int g  = tid & 255;
    const int ah = tid >> 8;
    const int arow = bm + ah * 128 + (g >> 3);
    const int acol = 8 * ((g & 7) ^ ((g >> 3) & 7));      // pre-swizzled source col
    const unsigned short* Asrc = A + (size_t)arow * K_DIM + acol;
    const int AdstE = ah * 8192 + g * 8;

    const int h = lane + 64 * wr;
    const int brow = bn + wc * 64 + (h >> 3);
    const int bcol = 8 * ((h & 7) ^ ((h >> 3) & 7));
    const unsigned short* Bsrc = B + (size_t)brow * K_DIM + bcol;
    const int BdstE = wc * 4096 + h * 8;

#define SA(dstb, j, kg) gload_lds16(Asrc + (size_t)(32*(j))*K_DIM + (kg), (dstb) + AdstE + 2048*(j))
#define SB(dstb, j, kg) gload_lds16(Bsrc + (size_t)(16*(j))*K_DIM + (kg), (dstb) + BdstE + 1024*(j))

    // fragment read offsets (row&7 == fr&7 -> swizzle slot is thread-constant)
    const int fr  = lane & 15;
    const int kq4 = lane >> 4;
    const int rowOffA = (wr * 128 + fr) * 64;
    const int rowOffB = (wc * 64 + fr) * 64;
    const int sk0 = 8 * ((kq4    ) ^ (fr & 7));
    const int sk1 = 8 * ((kq4 + 4) ^ (fr & 7));

    f32x4 acc[8][4] = {};

    bf16x8 bfr[4][2];
    // kk-split MFMA: dependency distance 8 instructions between kk0 and kk1 use
#define MFMA16(q, A00, A10, A01, A11)                                                              \
    __builtin_amdgcn_s_setprio(1);                                                                 \
    _Pragma("unroll")                                                                              \
    for (int n = 0; n < 4; ++n) {                                                                  \
        acc[2*(q)][n]   = __builtin_amdgcn_mfma_f32_16x16x32_bf16(A00, bfr[n][0], acc[2*(q)][n], 0, 0, 0);   \
        acc[2*(q)+1][n] = __builtin_amdgcn_mfma_f32_16x16x32_bf16(A10, bfr[n][0], acc[2*(q)+1][n], 0, 0, 0); \
    }                                                                                              \
    _Pragma("unroll")                                                                              \
    for (int n = 0; n < 4; ++n) {                                                                  \
        acc[2*(q)][n]   = __builtin_amdgcn_mfma_f32_16x16x32_bf16(A01, bfr[n][1], acc[2*(q)][n], 0, 0, 0);   \
        acc[2*(q)+1][n] = __builtin_amdgcn_mfma_f32_16x16x32_bf16(A11, bfr[n][1], acc[2*(q)+1][n], 0, 0, 0); \
    }                                                                                              \
    __builtin_amdgcn_s_setprio(0);

    // ---- prologue: stage tile0 into buf0; land B0-3,A0,A1; pre-read j0 frags
    SB(lds + 32768, 0, 0); SB(lds + 32768, 1, 0); SB(lds + 32768, 2, 0); SB(lds + 32768, 3, 0);
    SA(lds,         0, 0); SA(lds,         1, 0); SA(lds,         2, 0); SA(lds,         3, 0);
    asm volatile("s_waitcnt vmcnt(2)" ::: "memory");
    asm volatile("s_barrier" ::: "memory");

    // loop-carried pre-read set (j0 frags of upcoming tile)
    bf16x8 p00 = ld8(lds + rowOffA + 0 * 1024 + sk0);
    bf16x8 p10 = ld8(lds + rowOffA + 1 * 1024 + sk0);
    bf16x8 p01 = ld8(lds + rowOffA + 0 * 1024 + sk1);
    bf16x8 p11 = ld8(lds + rowOffA + 1 * 1024 + sk1);

    for (int t = 0; t < 64; ++t) {
        const int cur = t & 1, nxt = cur ^ 1;
        const unsigned short* Ab  = lds + cur * 16384;
        const unsigned short* Bb  = lds + 32768 + cur * 16384;
        unsigned short* AbN = lds + nxt * 16384;
        unsigned short* BbN = lds + 32768 + nxt * 16384;
        const unsigned short* AbNr = AbN;
        const int kn = (t < 63 ? t + 1 : 63) * 64;   // clamped: last stage is dead data

        // ---------- phase 0: MFMA j0 (p-set); read B(t) + A(t)-j1; stage B'x4
        {
#pragma unroll
            for (int n = 0; n < 4; ++n) {
                bfr[n][0] = ld8(Bb + rowOffB + n * 1024 + sk0);
                bfr[n][1] = ld8(Bb + rowOffB + n * 1024 + sk1);
            }
            bf16x8 q00 = ld8(Ab + rowOffA + 2 * 1024 + sk0);
            bf16x8 q10 = ld8(Ab + rowOffA + 3 * 1024 + sk0);
            bf16x8 q01 = ld8(Ab + rowOffA + 2 * 1024 + sk1);
            bf16x8 q11 = ld8(Ab + rowOffA + 3 * 1024 + sk1);
            SB(BbN, 0, kn); SB(BbN, 1, kn); SB(BbN, 2, kn); SB(BbN, 3, kn);
            MFMA16(0, p00, p10, p01, p11);
            asm volatile("s_waitcnt vmcnt(5)" ::: "memory");
            asm volatile("s_barrier" ::: "memory");

            // ---------- phase 1: MFMA j1 (q-set); read A(t)-j2; stage A'0,A'1
            bf16x8 r00 = ld8(Ab + rowOffA + 4 * 1024 + sk0);
            bf16x8 r10 = ld8(Ab + rowOffA + 5 * 1024 + sk0);
            bf16x8 r01 = ld8(Ab + rowOffA + 4 * 1024 + sk1);
            bf16x8 r11 = ld8(Ab + rowOffA + 5 * 1024 + sk1);
            SA(AbN, 0, kn); SA(AbN, 1, kn);
            MFMA16(1, q00, q10, q01, q11);
            asm volatile("s_waitcnt vmcnt(6)" ::: "memory");
            asm volatile("s_barrier" ::: "memory");

            // ---------- phase 2: MFMA j2 (r-set); read A(t)-j3; stage A'2,A'3
            bf16x8 s00 = ld8(Ab + rowOffA + 6 * 1024 + sk0);
            bf16x8 s10 = ld8(Ab + rowOffA + 7 * 1024 + sk0);
            bf16x8 s01 = ld8(Ab + rowOffA + 6 * 1024 + sk1);
            bf16x8 s11 = ld8(Ab + rowOffA + 7 * 1024 + sk1);
            SA(AbN, 2, kn); SA(AbN, 3, kn);
            MFMA16(2, r00, r10, r01, r11);
            asm volatile("s_waitcnt vmcnt(3)" ::: "memory");
            asm volatile("s_barrier" ::: "memory");

            // ---------- phase 3: MFMA j3 (s-set); pre-read A(t+1)-j0 from next buf
            p00 = ld8(AbNr + rowOffA + 0 * 1024 + sk0);
            p10 = ld8(AbNr + rowOffA + 1 * 1024 + sk0);
            p01 = ld8(AbNr + rowOffA + 0 * 1024 + sk1);
            p11 = ld8(AbNr + rowOffA + 1 * 1024 + sk1);
            MFMA16(3, s00, s10, s01, s11);
            asm volatile("s_waitcnt vmcnt(2)" ::: "memory");
            asm volatile("s_barrier" ::: "memory");
        }
    }

    asm volatile("s_waitcnt vmcnt(0)" ::: "memory");  // drain dead tail stages

    // C/D layout (m89): col = lane&15, row = (lane>>4)*4 + j
    const int crow = bm + wr * 128 + kq4 * 4;
    const int ccol = bn + wc * 64 + fr;
#pragma unroll
    for (int m = 0; m < 8; ++m)
#pragma unroll
        for (int n = 0; n < 4; ++n)
#pragma unroll
            for (int j = 0; j < 4; ++j)
                C[(size_t)(crow + m * 16 + j) * N_DIM + ccol + n * 16] = acc[m][n][j];
}

// ---------------------------------------------------------------------------
// fp32 fallback (only if ws too small)
// ---------------------------------------------------------------------------
__global__ void gemm_f32_fallback(const float* __restrict__ A,
                                  const float* __restrict__ B,
                                  float* __restrict__ C,
                                  const float* __restrict__ thrp) {
    __shared__ float As[32][33];
    __shared__ float Bs[32][33];
    const float thr = thrp[0];
    const int tx = threadIdx.x, ty = threadIdx.y;
    const int row = blockIdx.y * 32 + ty;
    float acc = 0.0f;
    for (int k0 = 0; k0 < K_DIM; k0 += 32) {
        float a = A[(size_t)row * K_DIM + k0 + tx];
        As[ty][tx] = (fabsf(a) > thr) ? a : 0.0f;
        Bs[ty][tx] = B[(size_t)(blockIdx.x * 32 + ty) * K_DIM + k0 + tx];
        __syncthreads();
#pragma unroll 8
        for (int kk = 0; kk < 32; ++kk)
            acc += As[ty][kk] * Bs[tx][kk];
        __syncthreads();
    }
    C[(size_t)row * N_DIM + blockIdx.x * 32 + tx] = acc;
}

// ---------------------------------------------------------------------------
extern "C" void kernel_launch(void* const* d_in, const int* in_sizes, int n_in,
                              void* d_out, int out_size, void* d_ws, size_t ws_size,
                              hipStream_t stream) {
    const float* x    = (const float*)d_in[0];
    const float* w    = (const float*)d_in[1];
    const float* thrp = (const float*)d_in[2];
    float* out = (float*)d_out;

    const size_t elems = (size_t)M_DIM * K_DIM;
    if (ws_size >= 2 * elems * sizeof(unsigned short)) {
        unsigned short* Ab = (unsigned short*)d_ws;
        unsigned short* Bb = Ab + elems;
        const int n8 = (int)(elems / 8);
        prune_cvt2<<<2048, 256, 0, stream>>>(x, w, Ab, Bb, thrp, n8);
        gemm_8phase<<<dim3(256), dim3(512), 0, stream>>>(Ab, Bb, out);
    } else {
        dim3 grid(N_DIM / 32, M_DIM / 32), blk(32, 32);
        gemm_f32_fallback<<<grid, blk, 0, stream>>>(x, w, out, thrp);
    }
}